// Round 7
// baseline (287.786 us; speedup 1.0000x reference)
//
#include <hip/hip_runtime.h>
#include <math.h>

#define N_NODES 10000
#define N_EDGES 50000
#define IN_F    1433
#define OUT_F   256
#define GK      1440          // padded K: multiple of 32, rows 16B-aligned
#define NCHUNK  180           // GK/8
#define GM2     10112         // 79*128: agg rows padded to GEMM M tiles

typedef __bf16 bf16x8 __attribute__((ext_vector_type(8)));
typedef float  f32x4  __attribute__((ext_vector_type(4)));

typedef __attribute__((address_space(3))) unsigned int lds_u32;
typedef __attribute__((address_space(1))) unsigned int glb_u32;

__device__ __forceinline__ void stage16(const void* g, void* l) {
    __builtin_amdgcn_global_load_lds((glb_u32*)g, (lds_u32*)l, 16, 0, 0);
}

// ---------------- CSR build: single-block kernel, counts in LDS ---------------
// zero -> hist (LDS atomics) -> shuffle scan -> fill (LDS cursor)

__global__ void __launch_bounds__(1024) k_csr(const int* __restrict__ edges,
                                              int* __restrict__ offsets,
                                              int* __restrict__ edge_src) {
    __shared__ int cnt[N_NODES];   // 40000 B
    __shared__ int wsum[16];
    __shared__ int carry_s;
    const int t = threadIdx.x, lane = t & 63, wid = t >> 6;

    for (int i = t; i < N_NODES; i += 1024) cnt[i] = 0;
    if (t == 0) carry_s = 0;
    __syncthreads();

    for (int e = t; e < N_EDGES; e += 1024) {
        int dst = edges[2 * e];
        int src = edges[2 * e + 1];
        if (src < N_NODES) atomicAdd(&cnt[dst], 1);
    }
    __syncthreads();

    // exclusive scan of cnt; offsets -> global, cursor stays in cnt
    for (int base = 0; base < N_NODES; base += 1024) {
        int i = base + t;
        int v = (i < N_NODES) ? cnt[i] : 0;
        int s = v;
#pragma unroll
        for (int off = 1; off < 64; off <<= 1) {
            int u = __shfl_up(s, off, 64);
            if (lane >= off) s += u;
        }
        if (lane == 63) wsum[wid] = s;
        __syncthreads();
        if (t == 0) {
            int run = carry_s;
#pragma unroll
            for (int w2 = 0; w2 < 16; ++w2) { int tmp = wsum[w2]; wsum[w2] = run; run += tmp; }
            carry_s = run;
        }
        __syncthreads();
        int excl = wsum[wid] + s - v;
        if (i < N_NODES) { offsets[i] = excl; cnt[i] = excl; }
        __syncthreads();
    }
    if (t == 0) offsets[N_NODES] = carry_s;
    __syncthreads();

    for (int e = t; e < N_EDGES; e += 1024) {
        int dst = edges[2 * e];
        int src = edges[2 * e + 1];
        if (src < N_NODES) {
            int pos = atomicAdd(&cnt[dst], 1);
            edge_src[pos] = src;
        }
    }
}

// ---------------- fp32 -> bf16 convert: register window-select, no LDS --------
// wave w of block owns source row r = blk*4 + w. Row start mod 4 == r%4 == d
// (1433 % 4 == 1), wave-uniform -> uniform branch selects dwords [d..d+7] from
// 3 aligned float4 loads. Chunk 179 (row-crossing) takes a 1-dword path.
// Max read dword = 14,329,999 == last array element: in-bounds by construction.

__global__ void __launch_bounds__(256) k_conv(const float* __restrict__ X,
                                              const float* __restrict__ noise,
                                              __bf16* __restrict__ Xbf) {
    const int t = threadIdx.x;
    const int w = t >> 6, lane = t & 63;
    const int r = blockIdx.x * 4 + w;            // 0..9999
    const int rbase = blockIdx.y ? N_NODES : 0;
    const float* src = blockIdx.y ? noise : X;
    const size_t rowf = (size_t)r * IN_F;
    __bf16* orow = Xbf + (size_t)(rbase + r) * GK;
    const int d = r & 3;

#pragma unroll
    for (int s2 = 0; s2 < 3; ++s2) {
        int k = lane + s2 * 64;
        if (k < 179) {
            size_t q0 = (rowf + (size_t)k * 8) >> 2;
            f32x4 a = ((const f32x4*)src)[q0];
            f32x4 b = ((const f32x4*)src)[q0 + 1];
            f32x4 c = ((const f32x4*)src)[q0 + 2];
            float q[12];
            *(f32x4*)&q[0] = a; *(f32x4*)&q[4] = b; *(f32x4*)&q[8] = c;
            bf16x8 v;
            switch (d) {
            case 0:
#pragma unroll
                for (int j = 0; j < 8; ++j) v[j] = (__bf16)q[0 + j];
                break;
            case 1:
#pragma unroll
                for (int j = 0; j < 8; ++j) v[j] = (__bf16)q[1 + j];
                break;
            case 2:
#pragma unroll
                for (int j = 0; j < 8; ++j) v[j] = (__bf16)q[2 + j];
                break;
            default:
#pragma unroll
                for (int j = 0; j < 8; ++j) v[j] = (__bf16)q[3 + j];
                break;
            }
            *(bf16x8*)(orow + k * 8) = v;
        } else if (k == 179) {
            float x = src[rowf + 1432];
            bf16x8 v;
            v[0] = (__bf16)x;
#pragma unroll
            for (int j = 1; j < 8; ++j) v[j] = (__bf16)0.0f;
            *(bf16x8*)(orow + 1432) = v;
        }
    }
}

// ---------------- prep: W^T (bf16, zero-padded K) only ------------------------

#define PREP_W  (OUT_F * GK)                 // 368640

__global__ void k_prep(const float* __restrict__ W, __bf16* __restrict__ BT) {
    int i = blockIdx.x * blockDim.x + threadIdx.x;
    if (i < PREP_W) {
        int n = i / GK, k = i % GK;
        BT[i] = (__bf16)((k < IN_F) ? W[(size_t)k * OUT_F + n] : 0.0f);
    }
}

// ---------------- aggregate: barrier-free, bf16x8 everywhere + fused norm -----
// agg[i] = noise[i] + sum_{src in N(i)} X[src];  rnorm[i] = 1/max(||agg||,1e-12)
// grid = GM2: blocks >= N_NODES just zero their pad row (GEMM reads them)

__global__ void __launch_bounds__(192) k_agg(const __bf16* __restrict__ Xbf,
                                             const int* __restrict__ offsets,
                                             const int* __restrict__ edge_src,
                                             __bf16* __restrict__ aggbf,
                                             float* __restrict__ rnorm) {
    __shared__ float red[3];
    const int node = blockIdx.x;
    const int t = threadIdx.x;
    const bool active = (t < NCHUNK);
    const size_t co = (size_t)t * 8;

    if (node >= N_NODES) {          // pad rows for the GEMM M-tiling
        if (active) {
            bf16x8 z;
#pragma unroll
            for (int j = 0; j < 8; ++j) z[j] = (__bf16)0.0f;
            *(bf16x8*)(aggbf + (size_t)node * GK + co) = z;
        }
        return;
    }

    const int beg = offsets[node], end = offsets[node + 1];

    float acc[8] = {0.f, 0.f, 0.f, 0.f, 0.f, 0.f, 0.f, 0.f};
    if (active) {
        bf16x8 v = *(const bf16x8*)(Xbf + (size_t)(N_NODES + node) * GK + co);
#pragma unroll
        for (int j = 0; j < 8; ++j) acc[j] = (float)v[j];
    }

    int kk = beg;
    for (; kk + 3 < end; kk += 4) {
        int n0 = edge_src[kk], n1 = edge_src[kk + 1];
        int n2 = edge_src[kk + 2], n3 = edge_src[kk + 3];
        if (active) {
            bf16x8 v0 = *(const bf16x8*)(Xbf + (size_t)n0 * GK + co);
            bf16x8 v1 = *(const bf16x8*)(Xbf + (size_t)n1 * GK + co);
            bf16x8 v2 = *(const bf16x8*)(Xbf + (size_t)n2 * GK + co);
            bf16x8 v3 = *(const bf16x8*)(Xbf + (size_t)n3 * GK + co);
#pragma unroll
            for (int j = 0; j < 8; ++j)
                acc[j] += ((float)v0[j] + (float)v1[j]) + ((float)v2[j] + (float)v3[j]);
        }
    }
    for (; kk < end; ++kk) {
        int n0 = edge_src[kk];
        if (active) {
            bf16x8 v = *(const bf16x8*)(Xbf + (size_t)n0 * GK + co);
#pragma unroll
            for (int j = 0; j < 8; ++j) acc[j] += (float)v[j];
        }
    }

    float ss = 0.f;
    if (active) {
        bf16x8 o;
#pragma unroll
        for (int j = 0; j < 8; ++j) { o[j] = (__bf16)acc[j]; ss += acc[j] * acc[j]; }
        *(bf16x8*)(aggbf + (size_t)node * GK + co) = o;
    }
    for (int off = 32; off > 0; off >>= 1) ss += __shfl_down(ss, off, 64);
    if ((t & 63) == 0) red[t >> 6] = ss;
    __syncthreads();
    if (t == 0)
        rnorm[node] = 1.0f / fmaxf(sqrtf(red[0] + red[1] + red[2]), 1e-12f);
}

// ---------------- bf16 MFMA GEMM: out = (aggbf @ WbfT^T) * rnorm + bias --------
// BM=128, BN=64, BK=32: 316 blocks; 4 waves, each 32x64 (2x4 of 16x16x32)

#define BK 32

__global__ void __launch_bounds__(256) k_gemm(const __bf16* __restrict__ A,
                                              const __bf16* __restrict__ BT,
                                              const float* __restrict__ rnorm,
                                              const float* __restrict__ bias,
                                              float* __restrict__ out) {
    __shared__ __align__(16) __bf16 Asm[128][BK];
    __shared__ __align__(16) __bf16 Bsm[64][BK];

    const int t = threadIdx.x;
    const int lane = t & 63;
    const int w = t >> 6;
    const int row0 = blockIdx.y * 128;
    const int col0 = blockIdx.x * 64;

    const int sm = t >> 2;        // 0..63
    const int sc = (t & 3) * 8;

    f32x4 acc[2][4];
#pragma unroll
    for (int i = 0; i < 2; ++i)
#pragma unroll
        for (int j = 0; j < 4; ++j) acc[i][j] = (f32x4){0.f, 0.f, 0.f, 0.f};

    __bf16* asm0 = (__bf16*)Asm;
    __bf16* bsm0 = (__bf16*)Bsm;

#pragma unroll
    for (int r = 0; r < 2; ++r)
        stage16(A + (size_t)(row0 + sm + r * 64) * GK + sc, asm0 + r * 2048 + t * 8);
    stage16(BT + (size_t)(col0 + sm) * GK + sc, bsm0 + t * 8);

    const int kq = (lane >> 4) * 8;
    const int l15 = lane & 15;

    for (int kt = 0; kt < GK / BK; ++kt) {
        __syncthreads();

        bf16x8 af[2], bfr[4];
#pragma unroll
        for (int i = 0; i < 2; ++i) af[i]  = *(const bf16x8*)&Asm[w * 32 + i * 16 + l15][kq];
#pragma unroll
        for (int j = 0; j < 4; ++j) bfr[j] = *(const bf16x8*)&Bsm[j * 16 + l15][kq];

        __syncthreads();

        if (kt + 1 < GK / BK) {
            int k0 = (kt + 1) * BK;
#pragma unroll
            for (int r = 0; r < 2; ++r)
                stage16(A + (size_t)(row0 + sm + r * 64) * GK + k0 + sc, asm0 + r * 2048 + t * 8);
            stage16(BT + (size_t)(col0 + sm) * GK + k0 + sc, bsm0 + t * 8);
        }

#pragma unroll
        for (int i = 0; i < 2; ++i)
#pragma unroll
            for (int j = 0; j < 4; ++j)
                acc[i][j] = __builtin_amdgcn_mfma_f32_16x16x32_bf16(af[i], bfr[j], acc[i][j], 0, 0, 0);
    }

    // epilogue: C/D layout col=lane&15, row=(lane>>4)*4+reg; fuse rnorm + bias
    const int rq4 = (lane >> 4) * 4;
#pragma unroll
    for (int i = 0; i < 2; ++i) {
        int gr0 = row0 + w * 32 + i * 16 + rq4;
#pragma unroll
        for (int r = 0; r < 4; ++r) {
            int gr = gr0 + r;
            if (gr < N_NODES) {
                float rn = rnorm[gr];
#pragma unroll
                for (int j = 0; j < 4; ++j) {
                    int gc = col0 + j * 16 + l15;
                    out[(size_t)gr * OUT_F + gc] = acc[i][j][r] * rn + bias[gc];
                }
            }
        }
    }
}

// ---------------- launch ----------------

extern "C" void kernel_launch(void* const* d_in, const int* in_sizes, int n_in,
                              void* d_out, int out_size, void* d_ws, size_t ws_size,
                              hipStream_t stream) {
    const float* feat  = (const float*)d_in[0];
    const int*   edges = (const int*)d_in[1];
    const float* W     = (const float*)d_in[2];
    const float* bias  = (const float*)d_in[3];
    const float* noise = (const float*)d_in[4];
    float* out = (float*)d_out;

    char* ws = (char*)d_ws;
    size_t off = 0;
    auto carve = [&](size_t bytes) {
        void* p = ws + off;
        off = (off + bytes + 255) & ~(size_t)255;
        return p;
    };
    __bf16* Xbf     = (__bf16*)carve((size_t)2 * N_NODES * GK * sizeof(__bf16));
    __bf16* aggbf   = (__bf16*)carve((size_t)GM2 * GK * sizeof(__bf16));
    __bf16* WbfT    = (__bf16*)carve((size_t)OUT_F * GK * sizeof(__bf16));
    float*  rnorm   = (float*)carve((size_t)N_NODES * sizeof(float));
    int*    offsets = (int*)carve((size_t)(N_NODES + 1) * sizeof(int));
    int*    edge_src= (int*)carve((size_t)N_EDGES * sizeof(int));
    (void)ws_size;

    const int TB = 256;
    k_csr<<<1, 1024, 0, stream>>>(edges, offsets, edge_src);

    dim3 cgrid(N_NODES / 4, 2);
    k_conv<<<cgrid, 256, 0, stream>>>(feat, noise, Xbf);

    k_prep<<<(PREP_W + TB - 1) / TB, TB, 0, stream>>>(W, WbfT);

    k_agg<<<GM2, 192, 0, stream>>>(Xbf, offsets, edge_src, aggbf, rnorm);

    dim3 ggrid(OUT_F / 64, GM2 / 128);
    k_gemm<<<ggrid, 256, 0, stream>>>(aggbf, WbfT, rnorm, bias, out);
}

// Round 8
// 231.231 us; speedup vs baseline: 1.2446x; 1.2446x over previous
//
#include <hip/hip_runtime.h>
#include <math.h>

#define N_NODES 10000
#define N_EDGES 50000
#define IN_F    1433
#define OUT_F   256
#define GK      1440          // padded K: multiple of 32, rows 16B-aligned
#define NCHUNK  180           // GK/8
#define GM2     10112         // 79*128: agg rows padded to GEMM M tiles

typedef __bf16 bf16x8 __attribute__((ext_vector_type(8)));
typedef float  f32x4  __attribute__((ext_vector_type(4)));

typedef __attribute__((address_space(3))) unsigned int lds_u32;
typedef __attribute__((address_space(1))) unsigned int glb_u32;

__device__ __forceinline__ void stage16(const void* g, void* l) {
    __builtin_amdgcn_global_load_lds((glb_u32*)g, (lds_u32*)l, 16, 0, 0);
}

// ---------------- CSR build (multi-kernel, grid-wide) ----------------

__global__ void k_zero(int* __restrict__ counts, int n) {
    int i = blockIdx.x * blockDim.x + threadIdx.x;
    if (i < n) counts[i] = 0;
}

__global__ void k_hist(const int* __restrict__ edges, int* __restrict__ counts) {
    int e = blockIdx.x * blockDim.x + threadIdx.x;
    if (e < N_EDGES) {
        int dst = edges[2 * e];
        int src = edges[2 * e + 1];
        if (src < N_NODES) atomicAdd(&counts[dst], 1);
    }
}

// shuffle-based single-block scan: 3 syncs per 1024-chunk (10 chunks, trivial)
__global__ void __launch_bounds__(1024) k_scan(const int* __restrict__ counts,
                                               int* __restrict__ offsets,
                                               int* __restrict__ cursor) {
    __shared__ int wsum[16];
    __shared__ int carry_s;
    const int t = threadIdx.x, lane = t & 63, wid = t >> 6;
    if (t == 0) carry_s = 0;
    __syncthreads();
    for (int base = 0; base < N_NODES; base += 1024) {
        int i = base + t;
        int v = (i < N_NODES) ? counts[i] : 0;
        int s = v;
#pragma unroll
        for (int off = 1; off < 64; off <<= 1) {
            int u = __shfl_up(s, off, 64);
            if (lane >= off) s += u;
        }
        if (lane == 63) wsum[wid] = s;
        __syncthreads();
        if (t == 0) {
            int run = carry_s;
#pragma unroll
            for (int w2 = 0; w2 < 16; ++w2) { int tmp = wsum[w2]; wsum[w2] = run; run += tmp; }
            carry_s = run;
        }
        __syncthreads();
        int excl = wsum[wid] + s - v;
        if (i < N_NODES) { offsets[i] = excl; cursor[i] = excl; }
        __syncthreads();
    }
    if (t == 0) offsets[N_NODES] = carry_s;
}

__global__ void k_fill(const int* __restrict__ edges, int* __restrict__ cursor,
                       int* __restrict__ edge_src) {
    int e = blockIdx.x * blockDim.x + threadIdx.x;
    if (e < N_EDGES) {
        int dst = edges[2 * e];
        int src = edges[2 * e + 1];
        if (src < N_NODES) {
            int pos = atomicAdd(&cursor[dst], 1);
            edge_src[pos] = src;
        }
    }
}

// ---------------- fp32 -> bf16 convert: register window-select, no LDS --------
// wave w of block owns source row r = blk*4 + w. Row start mod 4 == r%4 == d
// (1433 % 4 == 1), wave-uniform -> uniform branch selects dwords [d..d+7] from
// 3 aligned float4 loads. Chunk 179 (row-crossing) takes a 1-dword path.
// Max read dword = 14,329,999 == last array element: in-bounds by construction.

__global__ void __launch_bounds__(256) k_conv(const float* __restrict__ X,
                                              const float* __restrict__ noise,
                                              __bf16* __restrict__ Xbf) {
    const int t = threadIdx.x;
    const int w = t >> 6, lane = t & 63;
    const int r = blockIdx.x * 4 + w;            // 0..9999
    const int rbase = blockIdx.y ? N_NODES : 0;
    const float* src = blockIdx.y ? noise : X;
    const size_t rowf = (size_t)r * IN_F;
    __bf16* orow = Xbf + (size_t)(rbase + r) * GK;
    const int d = r & 3;

#pragma unroll
    for (int s2 = 0; s2 < 3; ++s2) {
        int k = lane + s2 * 64;
        if (k < 179) {
            size_t q0 = (rowf + (size_t)k * 8) >> 2;
            f32x4 a = ((const f32x4*)src)[q0];
            f32x4 b = ((const f32x4*)src)[q0 + 1];
            f32x4 c = ((const f32x4*)src)[q0 + 2];
            float q[12];
            *(f32x4*)&q[0] = a; *(f32x4*)&q[4] = b; *(f32x4*)&q[8] = c;
            bf16x8 v;
            switch (d) {
            case 0:
#pragma unroll
                for (int j = 0; j < 8; ++j) v[j] = (__bf16)q[0 + j];
                break;
            case 1:
#pragma unroll
                for (int j = 0; j < 8; ++j) v[j] = (__bf16)q[1 + j];
                break;
            case 2:
#pragma unroll
                for (int j = 0; j < 8; ++j) v[j] = (__bf16)q[2 + j];
                break;
            default:
#pragma unroll
                for (int j = 0; j < 8; ++j) v[j] = (__bf16)q[3 + j];
                break;
            }
            *(bf16x8*)(orow + k * 8) = v;
        } else if (k == 179) {
            float x = src[rowf + 1432];
            bf16x8 v;
            v[0] = (__bf16)x;
#pragma unroll
            for (int j = 1; j < 8; ++j) v[j] = (__bf16)0.0f;
            *(bf16x8*)(orow + 1432) = v;
        }
    }
}

// ---------------- prep: W^T (bf16, zero-padded K) only ------------------------

#define PREP_W  (OUT_F * GK)                 // 368640

__global__ void k_prep(const float* __restrict__ W, __bf16* __restrict__ BT) {
    int i = blockIdx.x * blockDim.x + threadIdx.x;
    if (i < PREP_W) {
        int n = i / GK, k = i % GK;
        BT[i] = (__bf16)((k < IN_F) ? W[(size_t)k * OUT_F + n] : 0.0f);
    }
}

// ---------------- aggregate: barrier-free, bf16x8 everywhere + fused norm -----
// agg[i] = noise[i] + sum_{src in N(i)} X[src];  rnorm[i] = 1/max(||agg||,1e-12)
// grid = GM2: blocks >= N_NODES just zero their pad row (GEMM reads them)

__global__ void __launch_bounds__(192) k_agg(const __bf16* __restrict__ Xbf,
                                             const int* __restrict__ offsets,
                                             const int* __restrict__ edge_src,
                                             __bf16* __restrict__ aggbf,
                                             float* __restrict__ rnorm) {
    __shared__ float red[3];
    const int node = blockIdx.x;
    const int t = threadIdx.x;
    const bool active = (t < NCHUNK);
    const size_t co = (size_t)t * 8;

    if (node >= N_NODES) {          // pad rows for the GEMM M-tiling
        if (active) {
            bf16x8 z;
#pragma unroll
            for (int j = 0; j < 8; ++j) z[j] = (__bf16)0.0f;
            *(bf16x8*)(aggbf + (size_t)node * GK + co) = z;
        }
        return;
    }

    const int beg = offsets[node], end = offsets[node + 1];

    float acc[8] = {0.f, 0.f, 0.f, 0.f, 0.f, 0.f, 0.f, 0.f};
    if (active) {
        bf16x8 v = *(const bf16x8*)(Xbf + (size_t)(N_NODES + node) * GK + co);
#pragma unroll
        for (int j = 0; j < 8; ++j) acc[j] = (float)v[j];
    }

    int kk = beg;
    for (; kk + 3 < end; kk += 4) {
        int n0 = edge_src[kk], n1 = edge_src[kk + 1];
        int n2 = edge_src[kk + 2], n3 = edge_src[kk + 3];
        if (active) {
            bf16x8 v0 = *(const bf16x8*)(Xbf + (size_t)n0 * GK + co);
            bf16x8 v1 = *(const bf16x8*)(Xbf + (size_t)n1 * GK + co);
            bf16x8 v2 = *(const bf16x8*)(Xbf + (size_t)n2 * GK + co);
            bf16x8 v3 = *(const bf16x8*)(Xbf + (size_t)n3 * GK + co);
#pragma unroll
            for (int j = 0; j < 8; ++j)
                acc[j] += ((float)v0[j] + (float)v1[j]) + ((float)v2[j] + (float)v3[j]);
        }
    }
    for (; kk < end; ++kk) {
        int n0 = edge_src[kk];
        if (active) {
            bf16x8 v = *(const bf16x8*)(Xbf + (size_t)n0 * GK + co);
#pragma unroll
            for (int j = 0; j < 8; ++j) acc[j] += (float)v[j];
        }
    }

    float ss = 0.f;
    if (active) {
        bf16x8 o;
#pragma unroll
        for (int j = 0; j < 8; ++j) { o[j] = (__bf16)acc[j]; ss += acc[j] * acc[j]; }
        *(bf16x8*)(aggbf + (size_t)node * GK + co) = o;
    }
    for (int off = 32; off > 0; off >>= 1) ss += __shfl_down(ss, off, 64);
    if ((t & 63) == 0) red[t >> 6] = ss;
    __syncthreads();
    if (t == 0)
        rnorm[node] = 1.0f / fmaxf(sqrtf(red[0] + red[1] + red[2]), 1e-12f);
}

// ---------------- bf16 MFMA GEMM: out = (aggbf @ WbfT^T) * rnorm + bias --------
// BM=128, BN=64, BK=32: 316 blocks; 4 waves, each 32x64 (2x4 of 16x16x32)

#define BK 32

__global__ void __launch_bounds__(256) k_gemm(const __bf16* __restrict__ A,
                                              const __bf16* __restrict__ BT,
                                              const float* __restrict__ rnorm,
                                              const float* __restrict__ bias,
                                              float* __restrict__ out) {
    __shared__ __align__(16) __bf16 Asm[128][BK];
    __shared__ __align__(16) __bf16 Bsm[64][BK];

    const int t = threadIdx.x;
    const int lane = t & 63;
    const int w = t >> 6;
    const int row0 = blockIdx.y * 128;
    const int col0 = blockIdx.x * 64;

    const int sm = t >> 2;        // 0..63
    const int sc = (t & 3) * 8;

    f32x4 acc[2][4];
#pragma unroll
    for (int i = 0; i < 2; ++i)
#pragma unroll
        for (int j = 0; j < 4; ++j) acc[i][j] = (f32x4){0.f, 0.f, 0.f, 0.f};

    __bf16* asm0 = (__bf16*)Asm;
    __bf16* bsm0 = (__bf16*)Bsm;

#pragma unroll
    for (int r = 0; r < 2; ++r)
        stage16(A + (size_t)(row0 + sm + r * 64) * GK + sc, asm0 + r * 2048 + t * 8);
    stage16(BT + (size_t)(col0 + sm) * GK + sc, bsm0 + t * 8);

    const int kq = (lane >> 4) * 8;
    const int l15 = lane & 15;

    for (int kt = 0; kt < GK / BK; ++kt) {
        __syncthreads();

        bf16x8 af[2], bfr[4];
#pragma unroll
        for (int i = 0; i < 2; ++i) af[i]  = *(const bf16x8*)&Asm[w * 32 + i * 16 + l15][kq];
#pragma unroll
        for (int j = 0; j < 4; ++j) bfr[j] = *(const bf16x8*)&Bsm[j * 16 + l15][kq];

        __syncthreads();

        if (kt + 1 < GK / BK) {
            int k0 = (kt + 1) * BK;
#pragma unroll
            for (int r = 0; r < 2; ++r)
                stage16(A + (size_t)(row0 + sm + r * 64) * GK + k0 + sc, asm0 + r * 2048 + t * 8);
            stage16(BT + (size_t)(col0 + sm) * GK + k0 + sc, bsm0 + t * 8);
        }

#pragma unroll
        for (int i = 0; i < 2; ++i)
#pragma unroll
            for (int j = 0; j < 4; ++j)
                acc[i][j] = __builtin_amdgcn_mfma_f32_16x16x32_bf16(af[i], bfr[j], acc[i][j], 0, 0, 0);
    }

    // epilogue: C/D layout col=lane&15, row=(lane>>4)*4+reg; fuse rnorm + bias
    const int rq4 = (lane >> 4) * 4;
#pragma unroll
    for (int i = 0; i < 2; ++i) {
        int gr0 = row0 + w * 32 + i * 16 + rq4;
#pragma unroll
        for (int r = 0; r < 4; ++r) {
            int gr = gr0 + r;
            if (gr < N_NODES) {
                float rn = rnorm[gr];
#pragma unroll
                for (int j = 0; j < 4; ++j) {
                    int gc = col0 + j * 16 + l15;
                    out[(size_t)gr * OUT_F + gc] = acc[i][j][r] * rn + bias[gc];
                }
            }
        }
    }
}

// ---------------- launch ----------------

extern "C" void kernel_launch(void* const* d_in, const int* in_sizes, int n_in,
                              void* d_out, int out_size, void* d_ws, size_t ws_size,
                              hipStream_t stream) {
    const float* feat  = (const float*)d_in[0];
    const int*   edges = (const int*)d_in[1];
    const float* W     = (const float*)d_in[2];
    const float* bias  = (const float*)d_in[3];
    const float* noise = (const float*)d_in[4];
    float* out = (float*)d_out;

    char* ws = (char*)d_ws;
    size_t off = 0;
    auto carve = [&](size_t bytes) {
        void* p = ws + off;
        off = (off + bytes + 255) & ~(size_t)255;
        return p;
    };
    __bf16* Xbf     = (__bf16*)carve((size_t)2 * N_NODES * GK * sizeof(__bf16));
    __bf16* aggbf   = (__bf16*)carve((size_t)GM2 * GK * sizeof(__bf16));
    __bf16* WbfT    = (__bf16*)carve((size_t)OUT_F * GK * sizeof(__bf16));
    float*  rnorm   = (float*)carve((size_t)N_NODES * sizeof(float));
    int*    counts  = (int*)carve((size_t)(N_NODES + 1) * sizeof(int));
    int*    offsets = (int*)carve((size_t)(N_NODES + 1) * sizeof(int));
    int*    cursor  = (int*)carve((size_t)(N_NODES + 1) * sizeof(int));
    int*    edge_src= (int*)carve((size_t)N_EDGES * sizeof(int));
    (void)ws_size;

    const int TB = 256;
    k_zero<<<(N_NODES + 1 + TB - 1) / TB, TB, 0, stream>>>(counts, N_NODES + 1);
    k_hist<<<(N_EDGES + TB - 1) / TB, TB, 0, stream>>>(edges, counts);
    k_scan<<<1, 1024, 0, stream>>>(counts, offsets, cursor);
    k_fill<<<(N_EDGES + TB - 1) / TB, TB, 0, stream>>>(edges, cursor, edge_src);

    dim3 cgrid(N_NODES / 4, 2);
    k_conv<<<cgrid, 256, 0, stream>>>(feat, noise, Xbf);

    k_prep<<<(PREP_W + TB - 1) / TB, TB, 0, stream>>>(W, WbfT);

    k_agg<<<GM2, 192, 0, stream>>>(Xbf, offsets, edge_src, aggbf, rnorm);

    dim3 ggrid(OUT_F / 64, GM2 / 128);
    k_gemm<<<ggrid, 256, 0, stream>>>(aggbf, WbfT, rnorm, bias, out);
}